// Round 1
// 356.549 us; speedup vs baseline: 1.0009x; 1.0009x over previous
//
#include <hip/hip_runtime.h>
#include <hip/hip_bf16.h>

// Problem constants (fixed by reference setup_inputs)
constexpr int NN   = 50000;    // nodes
constexpr int NE   = 600000;   // edges
constexpr int NRBF = 50;       // rbf features
constexpr int DIM  = 128;      // embedding dim
constexpr float CUT = 5.0f;
constexpr float PI_F = 3.14159265358979323846f;

constexpr int CAP = 32;        // bucket capacity (active degree ~Poisson(10); P(>32)~1e-9, ovf fallback)
constexpr int NTILES = NE / 64;  // 9375 64-edge MFMA tiles

// Workspace layout (byte offsets). Total 180.3 MB (<= R5's proven 181.8 MB).
constexpr size_t OFF_DEG   = 0;                               // [NN] int
constexpr size_t OFF_OVFC  = (size_t)NN * 4;                  // [1] int (memset covers both)
constexpr size_t OFF_EID   = 200960;                          // [NN*CAP] int (6.4 MB)
constexpr size_t OFF_OVF   = OFF_EID  + (size_t)NN * CAP * 4; // [NE] int
constexpr size_t OFF_CC    = OFF_OVF  + (size_t)NE * 4;       // [NE] float
constexpr size_t OFF_EROW  = OFF_CC   + (size_t)NE * 4;       // [NE] int (-1 = inactive)
constexpr size_t OFF_WAUG  = OFF_EROW + (size_t)NE * 4;       // [128*64] bf16 (16 KB)
constexpr size_t OFF_EPERM = OFF_WAUG + 128 * 64 * 2;         // [100*128] bf16 permuted (25.6 KB)
constexpr size_t OFF_MSG   = 13843200;                        // [NE*128] bf16 permuted (153.6 MB)
constexpr size_t OFF_XI    = OFF_MSG  + (size_t)NE * DIM * 2; // [NN*128] bf16 normal order (12.8 MB)

// msg/emb_perm PERMUTED layout: position p holds dim delta(p) = 16*(p&7) + (p>>3).
// Lane c's positions 8c..8c+7 <-> dims {16q + c} = exactly its MFMA-D column across nt.

typedef __attribute__((ext_vector_type(4))) float f32x4;
typedef __attribute__((ext_vector_type(8))) short short8;

__device__ __forceinline__ float bf2f(unsigned short u) {
    return __uint_as_float(((unsigned int)u) << 16);
}
__device__ __forceinline__ unsigned short f2bf(float f) {
    return __bfloat16_as_ushort(__float2bfloat16(f));
}

// ---------------------------------------------------------------------------
// Kernel 0: prep small weights — W_aug[d][64] = [W_e[d][0..49] | b_e[d] | 0...],
// emb_perm[tau][p] = emb[tau][delta(p)], both bf16.
// ---------------------------------------------------------------------------
__global__ __launch_bounds__(256)
void prep_w(const float* __restrict__ W_e, const float* __restrict__ b_e,
            const float* __restrict__ emb,
            unsigned short* __restrict__ W_aug, unsigned short* __restrict__ emb_perm)
{
    const int tid = blockIdx.x * 256 + threadIdx.x;
    if (tid < 128 * 64) {
        const int d = tid >> 6, k = tid & 63;
        float v = 0.0f;
        if (k < NRBF)       v = W_e[d * NRBF + k];
        else if (k == NRBF) v = b_e[d];
        W_aug[tid] = f2bf(v);
    } else if (tid < 128 * 64 + 100 * 128) {
        const int i = tid - 128 * 64;
        const int tau = i >> 7, p = i & 127;
        const int d = 16 * (p & 7) + (p >> 3);
        emb_perm[i] = f2bf(emb[tau * DIM + d]);
    }
}

// ---------------------------------------------------------------------------
// Kernel 1: bucket active edges by dst; emit cc[e] and embrow[e] (-1 inactive).
// ---------------------------------------------------------------------------
__global__ __launch_bounds__(256)
void build_buckets(const int* __restrict__ dst, const float* __restrict__ dist,
                   const int* __restrict__ src, const int* __restrict__ node_type,
                   int* __restrict__ deg, int* __restrict__ eid,
                   int* __restrict__ ovf, int* __restrict__ ovf_cnt,
                   float* __restrict__ cc_arr, int* __restrict__ embrow)
{
    const int e = blockIdx.x * 256 + threadIdx.x;
    if (e >= NE) return;
    const float dd = dist[e];
    const bool act = dd < CUT;
    const float w = 0.5f * (__cosf(dd * (PI_F / CUT)) + 1.0f);
    cc_arr[e] = act ? w : 0.0f;
    embrow[e] = act ? node_type[src[e]] : -1;
    if (act) {
        const int n = dst[e];
        const int pos = atomicAdd(&deg[n], 1);
        if (pos < CAP) eid[n * CAP + pos] = e;
        else           ovf[atomicAdd(ovf_cnt, 1)] = e;
    }
}

// ---------------------------------------------------------------------------
// Kernel 2: edge message via MFMA. NEW (this round): rbf is staged to LDS with
// coalesced global_load_lds (width 16) instead of per-lane 8-B strided loads.
//
// Why: rocprof showed edge_msg latency-bound (MfmaUtil 3.9%, VALUBusy 15%,
// HBM 25%, occupancy 27%) — the ~7 strided dwordx2 loads per lane fragment
// into ~25 cache lines per wave-instruction and leave almost no bytes in
// flight. Staging a 64-edge tile (12,800 B contiguous, 16-B aligned) is 12.5
// coalesced 1-KB wave-instructions, double-buffered across tiles with counted
// s_waitcnt vmcnt(4).
//
// Crucial structural fact: wave wv computes rows wv*16..wv*16+15 of the tile,
// i.e. LDS bytes [wv*3200, wv*3200+3200) — exactly the chunks wave wv stages
// itself (chunk range [wv*200, wv*200+200)). So there is NO cross-wave LDS
// dependency: no barriers anywhere; each wave pipelines privately with its
// own vmcnt. B-fragments (W_aug, 16 KB L2-hot) stay register-resident.
// ---------------------------------------------------------------------------
__device__ __forceinline__ void stage_rbf(const float* __restrict__ rbf, int tt,
                                          void* lds_base, int wv, int l)
{
    // Tile tt = 64 rows x 200 B = 12800 B, globally contiguous and 16-B
    // aligned. Wave wv copies its own 3200 B (200 x 16-B chunks): 3 full
    // wave-instructions + 1 with 8 active lanes -> uniformly 4 vmcnt events
    // per wave per stage.
    const char* gb = (const char*)rbf + (size_t)tt * 12800 + (size_t)wv * 3200;
    char* lb = (char*)lds_base + wv * 3200;
    #pragma unroll
    for (int i = 0; i < 4; ++i) {
        if (i * 64 + l < 200) {
            __builtin_amdgcn_global_load_lds(
                (const __attribute__((address_space(1))) unsigned int*)(gb + (size_t)(i * 64 + l) * 16),
                (__attribute__((address_space(3))) unsigned int*)(lb + i * 1024),
                16, 0, 0);
        }
    }
}

__global__ __launch_bounds__(256)
void edge_msg_lds(const float* __restrict__ rbf,
                  const float* __restrict__ cc_arr,
                  const int* __restrict__ embrow,
                  const unsigned short* __restrict__ W_aug,
                  const unsigned short* __restrict__ emb_perm,
                  unsigned short* __restrict__ msg)
{
    __shared__ __align__(16) float sbuf[2][3200];   // 2 x 12.8 KB double buffer

    const int t  = threadIdx.x;
    const int wv = t >> 6, l = t & 63;
    const int c  = l & 15, g = l >> 4;

    // B fragments: row nt*16+c of W_aug, k-chunk [s*32+g*8 .. +7]. 16 KB, L2-hot.
    short8 bfrag[16];
    #pragma unroll
    for (int nt = 0; nt < 8; ++nt)
        #pragma unroll
        for (int s = 0; s < 2; ++s)
            bfrag[nt * 2 + s] =
                *(const short8*)(W_aug + (nt * 16 + c) * 64 + s * 32 + g * 8);

    const int tt0 = blockIdx.x * 4;

    // Prologue: stage first tile into buffer 0 (tt0 <= 9372 < NTILES always).
    stage_rbf(rbf, tt0, (void*)sbuf[0], wv, l);

    #pragma unroll
    for (int tile = 0; tile < 4; ++tile) {
        const int tt = tt0 + tile;

        // Issue next tile's staging into the other buffer, then wait for the
        // CURRENT tile's 4 staging loads (own wave only — private LDS strip).
        // vmcnt(4) also drains this wave's older epilogue loads/stores.
        if (tile < 3 && tt + 1 < NTILES) {
            stage_rbf(rbf, tt + 1, (void*)sbuf[(tile + 1) & 1], wv, l);
            asm volatile("s_waitcnt vmcnt(4)" ::: "memory");
        } else {
            asm volatile("s_waitcnt vmcnt(0)" ::: "memory");
        }

        if (tt < NTILES) {
            const int e0 = tt * 64;
            const int er = e0 + wv * 16 + c;         // this lane's A row (edge)
            const float ccl = cc_arr[er];            // 4 lanes/addr -> broadcast

            // epilogue metadata early (independent, L2-hot)
            const int4 er4 = *(const int4*)(embrow + e0 + wv * 16 + 4 * g);
            const int* erow = (const int*)&er4;

            // A raw loads from this wave's private LDS strip (ds_read_b64,
            // 8-B aligned: row stride 200 B).
            const float2* rp2 =
                (const float2*)((const char*)sbuf[tile & 1] + (wv * 16 + c) * 200);
            const float2 r0 = rp2[4 * g];
            const float2 r1 = rp2[4 * g + 1];
            const float2 r2 = rp2[4 * g + 2];
            const float2 r3 = rp2[4 * g + 3];
            float2 q0 = make_float2(0.f, 0.f), q1 = q0, q2 = q0, q3 = q0;
            if (g < 2) {
                q0 = rp2[16 + 4 * g];
                q1 = rp2[17 + 4 * g];
                q2 = rp2[18 + 4 * g];
                q3 = rp2[19 + 4 * g];
            } else if (g == 2) {
                q0 = rp2[24];                        // k48,k49
            }

            short8 a0, a1;
            a0[0] = (short)f2bf(ccl * r0.x); a0[1] = (short)f2bf(ccl * r0.y);
            a0[2] = (short)f2bf(ccl * r1.x); a0[3] = (short)f2bf(ccl * r1.y);
            a0[4] = (short)f2bf(ccl * r2.x); a0[5] = (short)f2bf(ccl * r2.y);
            a0[6] = (short)f2bf(ccl * r3.x); a0[7] = (short)f2bf(ccl * r3.y);
            a1[0] = (short)f2bf(ccl * q0.x); a1[1] = (short)f2bf(ccl * q0.y);
            a1[2] = (short)f2bf(ccl * q1.x); a1[3] = (short)f2bf(ccl * q1.y);
            a1[4] = (short)f2bf(ccl * q2.x); a1[5] = (short)f2bf(ccl * q2.y);
            a1[6] = (short)f2bf(ccl * q3.x); a1[7] = (short)f2bf(ccl * q3.y);
            if (g == 2) {                            // k50 = cc (b_e hook), k51+ = 0
                a1[2] = (short)f2bf(ccl);
                a1[3] = 0; a1[4] = 0; a1[5] = 0; a1[6] = 0; a1[7] = 0;
            }

            f32x4 acc[8] = {};
            #pragma unroll
            for (int nt = 0; nt < 8; ++nt)
                acc[nt] = __builtin_amdgcn_mfma_f32_16x16x32_bf16(a0, bfrag[nt * 2],
                                                                  acc[nt], 0, 0, 0);
            #pragma unroll
            for (int nt = 0; nt < 8; ++nt)
                acc[nt] = __builtin_amdgcn_mfma_f32_16x16x32_bf16(a1, bfrag[nt * 2 + 1],
                                                                  acc[nt], 0, 0, 0);

            // Epilogue: lane owns D col c for rows 4g..4g+3 of its wave strip.
            #pragma unroll
            for (int r = 0; r < 4; ++r) {
                const int e = e0 + wv * 16 + 4 * g + r;
                const int rw = erow[r];
                if (rw >= 0) {                       // active edge: store (zeros included)
                    const int4 em = *(const int4*)(emb_perm + rw * DIM + 8 * c);
                    const unsigned int* ep = (const unsigned int*)&em;
                    unsigned int ow[4];
                    #pragma unroll
                    for (int q = 0; q < 4; ++q) {
                        const float m0 = bf2f((unsigned short)(ep[q] & 0xffff));
                        const float m1 = bf2f((unsigned short)(ep[q] >> 16));
                        const float v0 = acc[2 * q][r] * m0;
                        const float v1 = acc[2 * q + 1][r] * m1;
                        ow[q] = (unsigned int)f2bf(v0) | ((unsigned int)f2bf(v1) << 16);
                    }
                    *(int4*)(msg + (size_t)e * DIM + 8 * c) =
                        make_int4((int)ow[0], (int)ow[1], (int)ow[2], (int)ow[3]);
                }
            }
        }
    }
}

// ---------------------------------------------------------------------------
// Kernel 3: gather-sum. 1 wave/node; lane group g handles edge j+g; lane loads
// int4 (16 B) of the permuted row; butterfly reduce over groups; store xi in
// NORMAL dim order (lane (c,g) -> dims 32g+c, 32g+16+c).
// ---------------------------------------------------------------------------
__global__ __launch_bounds__(256)
void gather_sum(const unsigned short* __restrict__ msg, const int* __restrict__ deg,
                const int* __restrict__ eid, const int* __restrict__ ovf,
                const int* __restrict__ ovf_cnt, const int* __restrict__ dst,
                unsigned short* __restrict__ xi)
{
    const int t = threadIdx.x, l = t & 63;
    const int c = l & 15, g = l >> 4;
    const int n = blockIdx.x * 4 + (t >> 6);
    if (n >= NN) return;

    const int dn   = deg[n];
    const int degn = dn < CAP ? dn : CAP;
    int eidv = 0;
    if (l < degn) eidv = eid[n * CAP + l];

    float v[8] = {};
    for (int j = 0; j < degn; j += 4) {
        const int e = __shfl(eidv, j + g);
        if (j + g < degn) {
            const int4 mv = *(const int4*)(msg + (size_t)e * DIM + 8 * c);
            const unsigned int* mp = (const unsigned int*)&mv;
            #pragma unroll
            for (int q = 0; q < 4; ++q) {
                v[2 * q]     += bf2f((unsigned short)(mp[q] & 0xffff));
                v[2 * q + 1] += bf2f((unsigned short)(mp[q] >> 16));
            }
        }
    }
    // Overflow fallback (deg > CAP): essentially never taken, kept for correctness.
    const int ocnt = ovf_cnt[0];
    for (int j = 0; j < ocnt; ++j) {
        const int e = ovf[j];
        if (g == 0 && dst[e] == n) {   // single group accumulates; butterfly counts once
            const int4 mv = *(const int4*)(msg + (size_t)e * DIM + 8 * c);
            const unsigned int* mp = (const unsigned int*)&mv;
            #pragma unroll
            for (int q = 0; q < 4; ++q) {
                v[2 * q]     += bf2f((unsigned short)(mp[q] & 0xffff));
                v[2 * q + 1] += bf2f((unsigned short)(mp[q] >> 16));
            }
        }
    }

    #pragma unroll
    for (int q = 0; q < 8; ++q) {
        v[q] += __shfl_xor(v[q], 16);
        v[q] += __shfl_xor(v[q], 32);
    }

    // lane (c,g): position 8c+q holds dim 16q+c; store q = 2g, 2g+1.
    float s0 = v[0], s1 = v[1];
    if (g == 1)      { s0 = v[2]; s1 = v[3]; }
    else if (g == 2) { s0 = v[4]; s1 = v[5]; }
    else if (g == 3) { s0 = v[6]; s1 = v[7]; }
    xi[(size_t)n * DIM + 32 * g + c]      = f2bf(s0);
    xi[(size_t)n * DIM + 32 * g + 16 + c] = f2bf(s1);
}

// ---------------------------------------------------------------------------
// Kernel 4: out[n] = [x_nodes[n] | xi[n]] @ W_c^T + b_c  via bf16 MFMA.
// (unchanged from R5 — known good)
// ---------------------------------------------------------------------------
__global__ __launch_bounds__(256)
void combine_mfma(const float* __restrict__ x_nodes, const __hip_bfloat16* __restrict__ xi,
                  const float* __restrict__ W_c, const float* __restrict__ b_c,
                  float* __restrict__ out)
{
    __shared__ unsigned short As[64][72];
    __shared__ unsigned short Bs[128][72];

    const int t  = threadIdx.x;
    const int wv = t >> 6;
    const int l  = t & 63;
    const int n0 = blockIdx.x * 64;

    f32x4 acc[8] = {};

    for (int kc = 0; kc < 4; ++kc) {
        const int kb = kc * 64;
        if (kc) __syncthreads();
        {
            const int r  = t >> 2;
            const int c0 = (t & 3) * 16;
            const int n  = n0 + r;
            if (kc < 2) {
                float4 v[4];
                if (n < NN) {
                    const float4* p = (const float4*)(x_nodes + (size_t)n * DIM + kb + c0);
                    v[0] = p[0]; v[1] = p[1]; v[2] = p[2]; v[3] = p[3];
                } else {
                    v[0] = v[1] = v[2] = v[3] = make_float4(0.f, 0.f, 0.f, 0.f);
                }
                unsigned short* dp = &As[r][c0];
                #pragma unroll
                for (int q = 0; q < 4; ++q) {
                    *(ushort2*)&dp[q * 4]     = make_ushort2(f2bf(v[q].x), f2bf(v[q].y));
                    *(ushort2*)&dp[q * 4 + 2] = make_ushort2(f2bf(v[q].z), f2bf(v[q].w));
                }
            } else {
                int4 v0 = make_int4(0, 0, 0, 0), v1 = make_int4(0, 0, 0, 0);
                if (n < NN) {
                    const int4* p = (const int4*)(xi + (size_t)n * DIM + (kb - DIM) + c0);
                    v0 = p[0];
                    v1 = p[1];
                }
                *(int4*)&As[r][c0]     = v0;
                *(int4*)&As[r][c0 + 8] = v1;
            }
        }
        {
            const int dch = t >> 1;
            const int c0  = (t & 1) * 32;
            const float4* p = (const float4*)(W_c + (size_t)dch * (2 * DIM) + kb + c0);
            unsigned short* dp = &Bs[dch][c0];
            #pragma unroll
            for (int q = 0; q < 8; ++q) {
                const float4 v = p[q];
                *(ushort2*)&dp[q * 4]     = make_ushort2(f2bf(v.x), f2bf(v.y));
                *(ushort2*)&dp[q * 4 + 2] = make_ushort2(f2bf(v.z), f2bf(v.w));
            }
        }
        __syncthreads();
        #pragma unroll
        for (int s = 0; s < 2; ++s) {
            const int ko = s * 32 + (l >> 4) * 8;
            const short8 af = *(const short8*)&As[wv * 16 + (l & 15)][ko];
            #pragma unroll
            for (int nt = 0; nt < 8; ++nt) {
                const short8 bf = *(const short8*)&Bs[nt * 16 + (l & 15)][ko];
                acc[nt] = __builtin_amdgcn_mfma_f32_16x16x32_bf16(af, bf, acc[nt], 0, 0, 0);
            }
        }
    }

    const int col = l & 15;
    const int rq  = (l >> 4) * 4;
    #pragma unroll
    for (int nt = 0; nt < 8; ++nt) {
        const int dim = nt * 16 + col;
        const float bc = b_c[dim];
        #pragma unroll
        for (int r = 0; r < 4; ++r) {
            const int node = n0 + wv * 16 + rq + r;
            if (node < NN)
                out[(size_t)node * DIM + dim] = acc[nt][r] + bc;
        }
    }
}

// ---------------------------------------------------------------------------
extern "C" void kernel_launch(void* const* d_in, const int* in_sizes, int n_in,
                              void* d_out, int out_size, void* d_ws, size_t ws_size,
                              hipStream_t stream)
{
    const int*   node_type = (const int*)  d_in[0];
    const float* x_nodes   = (const float*)d_in[1];
    const int*   src       = (const int*)  d_in[2];
    const int*   dst       = (const int*)  d_in[3];
    const float* rbf       = (const float*)d_in[4];
    const float* dist      = (const float*)d_in[5];
    const float* emb       = (const float*)d_in[6];
    const float* W_e       = (const float*)d_in[7];
    const float* b_e       = (const float*)d_in[8];
    const float* W_c       = (const float*)d_in[9];
    const float* b_c       = (const float*)d_in[10];
    float* out = (float*)d_out;

    char* ws = (char*)d_ws;
    int*            deg      = (int*)(ws + OFF_DEG);
    int*            ovf_cnt  = (int*)(ws + OFF_OVFC);
    int*            eid      = (int*)(ws + OFF_EID);
    int*            ovf      = (int*)(ws + OFF_OVF);
    float*          cc_arr   = (float*)(ws + OFF_CC);
    int*            embrow   = (int*)(ws + OFF_EROW);
    unsigned short* W_aug    = (unsigned short*)(ws + OFF_WAUG);
    unsigned short* emb_perm = (unsigned short*)(ws + OFF_EPERM);
    unsigned short* msg      = (unsigned short*)(ws + OFF_MSG);
    unsigned short* xi       = (unsigned short*)(ws + OFF_XI);

    hipMemsetAsync(deg, 0, (NN + 1) * sizeof(int), stream);

    prep_w<<<82, 256, 0, stream>>>(W_e, b_e, emb, W_aug, emb_perm);

    build_buckets<<<(NE + 255) / 256, 256, 0, stream>>>(
        dst, dist, src, node_type, deg, eid, ovf, ovf_cnt, cc_arr, embrow);

    edge_msg_lds<<<(NTILES + 3) / 4, 256, 0, stream>>>(
        rbf, cc_arr, embrow, W_aug, emb_perm, msg);

    gather_sum<<<(NN + 3) / 4, 256, 0, stream>>>(msg, deg, eid, ovf, ovf_cnt, dst, xi);

    combine_mfma<<<(NN + 63) / 64, 256, 0, stream>>>(
        x_nodes, (const __hip_bfloat16*)xi, W_c, b_c, out);
}